// Round 1
// baseline (706.642 us; speedup 1.0000x reference)
//
#include <hip/hip_runtime.h>
#include <hip/hip_bf16.h>

typedef __bf16 bf16;
typedef __bf16 bf16x4 __attribute__((ext_vector_type(4)));
typedef __bf16 bf16x8 __attribute__((ext_vector_type(8)));
typedef float f32x4 __attribute__((ext_vector_type(4)));

#define MFMA16(a, b, c) __builtin_amdgcn_mfma_f32_16x16x32_bf16(a, b, c, 0, 0, 0)

constexpr int DIM = 1024;
constexpr int NH = 16;
constexpr int HD = 64;
constexpr float SCALE = 0.125f;          // HEAD_DIM^-0.5
constexpr float L2E = 1.4426950408889634f;

// ---------------------------------------------------------------------------
// NT GEMM: C[M,1024] = A[M,1024] @ W[1024,1024]^T + bias
//   HEAD_OUT=true : write bf16, scattered to head-major [B, NH, Lq, 64]
//   HEAD_OUT=false: write fp32 row-major [M, 1024]
//   A_BF16: A operand is bf16 (attention output) instead of fp32
// 128x128 tile, 4 waves (2x2 of 64x64), BK=32, 16x16x32 bf16 MFMA.
// ---------------------------------------------------------------------------
template <bool HEAD_OUT, bool A_BF16>
__global__ __launch_bounds__(256) void gemm_nt(const void* __restrict__ Aptr,
                                               const float* __restrict__ W,
                                               const float* __restrict__ bias,
                                               void* __restrict__ Cptr, int Lq) {
  constexpr int KD = DIM;
  constexpr int LDT = 40;  // padded row stride (elems), 80B: 16B-aligned, bank-spread
  __shared__ bf16 As[128 * LDT];
  __shared__ bf16 Bs[128 * LDT];

  const int bm = blockIdx.x * 128;
  const int bn = blockIdx.y * 128;
  const int tid = threadIdx.x;
  const int w = tid >> 6;
  const int lane = tid & 63;
  const int quad = lane >> 4;
  const int l16 = lane & 15;
  const int wm = (w >> 1) * 64;
  const int wn = (w & 1) * 64;

  f32x4 acc[4][4] = {};

  for (int k0 = 0; k0 < KD; k0 += 32) {
    // ---- stage W tile (rows bn..bn+127, cols k0..k0+31), fp32 -> bf16
#pragma unroll
    for (int i = 0; i < 4; ++i) {
      int f = i * 256 + tid;              // float4 chunk id, 0..1023
      int row = f >> 3;
      int c4 = (f & 7) << 2;
      const float4 v = *(const float4*)(W + (size_t)(bn + row) * KD + k0 + c4);
      bf16x4 bv = {(bf16)v.x, (bf16)v.y, (bf16)v.z, (bf16)v.w};
      *(bf16x4*)&Bs[row * LDT + c4] = bv;
    }
    // ---- stage A tile
    if constexpr (A_BF16) {
      const bf16* A = (const bf16*)Aptr;
#pragma unroll
      for (int i = 0; i < 2; ++i) {
        int f = i * 256 + tid;            // 16B chunk id, 0..511
        int row = f >> 2;
        int c8 = (f & 3) << 3;
        bf16x8 v = *(const bf16x8*)(A + (size_t)(bm + row) * KD + k0 + c8);
        *(bf16x8*)&As[row * LDT + c8] = v;
      }
    } else {
      const float* A = (const float*)Aptr;
#pragma unroll
      for (int i = 0; i < 4; ++i) {
        int f = i * 256 + tid;
        int row = f >> 3;
        int c4 = (f & 7) << 2;
        const float4 v = *(const float4*)(A + (size_t)(bm + row) * KD + k0 + c4);
        bf16x4 av = {(bf16)v.x, (bf16)v.y, (bf16)v.z, (bf16)v.w};
        *(bf16x4*)&As[row * LDT + c4] = av;
      }
    }
    __syncthreads();

    // ---- fragments + MFMA
    bf16x8 af[4], bfrag[4];
#pragma unroll
    for (int mi = 0; mi < 4; ++mi)
      af[mi] = *(const bf16x8*)&As[(wm + mi * 16 + l16) * LDT + quad * 8];
#pragma unroll
    for (int ni = 0; ni < 4; ++ni)
      bfrag[ni] = *(const bf16x8*)&Bs[(wn + ni * 16 + l16) * LDT + quad * 8];
#pragma unroll
    for (int mi = 0; mi < 4; ++mi)
#pragma unroll
      for (int ni = 0; ni < 4; ++ni)
        acc[mi][ni] = MFMA16(af[mi], bfrag[ni], acc[mi][ni]);
    __syncthreads();
  }

  // ---- epilogue: C/D layout col = lane&15, row = quad*4 + r
#pragma unroll
  for (int mi = 0; mi < 4; ++mi) {
#pragma unroll
    for (int ni = 0; ni < 4; ++ni) {
      const int col = bn + wn + ni * 16 + l16;
      const float bv = bias[col];
#pragma unroll
      for (int r = 0; r < 4; ++r) {
        const int row = bm + wm + mi * 16 + quad * 4 + r;
        const float val = acc[mi][ni][r] + bv;
        if constexpr (HEAD_OUT) {
          const int b = row / Lq;
          const int l = row - b * Lq;
          const int h = col >> 6;
          const int d = col & 63;
          ((bf16*)Cptr)[((size_t)((b * NH + h) * Lq + l) << 6) + d] = (bf16)val;
        } else {
          ((float*)Cptr)[(size_t)row * DIM + col] = val;
        }
      }
    }
  }
}

// ---------------------------------------------------------------------------
// Flash-style cross attention.
// Q: bf16 [B, NH, 4096, 64]  K,V: bf16 [B, NH, 1024, 64]
// O: bf16 [B, 4096, 1024]   (col = h*64 + d, ready for final GEMM)
// grid: (L/64, NH, B), 256 threads = 4 waves, wave w owns q-rows w*16..w*16+15.
// ---------------------------------------------------------------------------
__global__ __launch_bounds__(256) void attn_fused(const bf16* __restrict__ Q,
                                                  const bf16* __restrict__ Kv,
                                                  const bf16* __restrict__ Vv,
                                                  bf16* __restrict__ O) {
  constexpr int LDV = 88;  // Vt row stride (elems): 176B, 16B-aligned, bank-spread
  __shared__ bf16 Vt[64 * LDV];   // transposed V tile: Vt[d][kv]
  __shared__ bf16 Ps[4][16 * 64]; // per-wave P tile [q_local][kv_local]

  const int qt = blockIdx.x;
  const int h = blockIdx.y;
  const int b = blockIdx.z;
  const int tid = threadIdx.x;
  const int w = tid >> 6;
  const int lane = tid & 63;
  const int quad = lane >> 4;
  const int l16 = lane & 15;

  const bf16* Qb = Q + ((size_t)(b * NH + h) * 4096 + qt * 64) * (size_t)HD;
  const bf16* Kb = Kv + (size_t)(b * NH + h) * 1024 * HD;
  const bf16* Vb = Vv + (size_t)(b * NH + h) * 1024 * HD;

  // Q A-fragments for this wave: A[m=l16][k=quad*8+j], k-chunks 0 and 32
  const bf16* qr = Qb + (size_t)(w * 16 + l16) * HD;
  const bf16x8 qf0 = *(const bf16x8*)(qr + quad * 8);
  const bf16x8 qf1 = *(const bf16x8*)(qr + 32 + quad * 8);

  f32x4 oacc[4] = {};
  float mrun[4], lrun[4];
#pragma unroll
  for (int r = 0; r < 4; ++r) {
    mrun[r] = -1e30f;
    lrun[r] = 0.f;
  }

  for (int kt = 0; kt < 1024; kt += 64) {
    __syncthreads();  // protect Vt from previous iteration's readers
    {
      // cooperative transpose-stage of V tile [64 kv][64 d] -> Vt[d][kv]
      const int kv = tid >> 2;
      const int d0 = (tid & 3) << 4;
      const bf16* src = Vb + (size_t)(kt + kv) * HD + d0;
      bf16x8 v0 = *(const bf16x8*)src;
      bf16x8 v1 = *(const bf16x8*)(src + 8);
#pragma unroll
      for (int j = 0; j < 8; ++j) Vt[(d0 + j) * LDV + kv] = v0[j];
#pragma unroll
      for (int j = 0; j < 8; ++j) Vt[(d0 + 8 + j) * LDV + kv] = v1[j];
    }
    __syncthreads();

    // ---- S = Q K^T (this wave's 16 rows x 64 kv cols)
    f32x4 s[4];
#pragma unroll
    for (int nt = 0; nt < 4; ++nt) {
      const bf16* kr = Kb + (size_t)(kt + nt * 16 + l16) * HD;  // B[k=d][n=kv]
      bf16x8 kf0 = *(const bf16x8*)(kr + quad * 8);
      bf16x8 kf1 = *(const bf16x8*)(kr + 32 + quad * 8);
      f32x4 a = {0.f, 0.f, 0.f, 0.f};
      a = MFMA16(qf0, kf0, a);
      a = MFMA16(qf1, kf1, a);
      s[nt] = a;
    }

    // ---- online softmax; row r of quad group = q_local quad*4+r
    float alpha[4];
#pragma unroll
    for (int r = 0; r < 4; ++r) {
      float mx = -1e30f;
#pragma unroll
      for (int nt = 0; nt < 4; ++nt) {
        s[nt][r] *= SCALE;
        mx = fmaxf(mx, s[nt][r]);
      }
      mx = fmaxf(mx, __shfl_xor(mx, 1));
      mx = fmaxf(mx, __shfl_xor(mx, 2));
      mx = fmaxf(mx, __shfl_xor(mx, 4));
      mx = fmaxf(mx, __shfl_xor(mx, 8));
      const float mnew = fmaxf(mrun[r], mx);
      alpha[r] = __builtin_exp2f((mrun[r] - mnew) * L2E);
      mrun[r] = mnew;
      float rs = 0.f;
#pragma unroll
      for (int nt = 0; nt < 4; ++nt) {
        float p = __builtin_exp2f((s[nt][r] - mnew) * L2E);
        rs += p;
        Ps[w][(quad * 4 + r) * 64 + nt * 16 + l16] = (bf16)p;
      }
      rs += __shfl_xor(rs, 1);
      rs += __shfl_xor(rs, 2);
      rs += __shfl_xor(rs, 4);
      rs += __shfl_xor(rs, 8);
      lrun[r] = lrun[r] * alpha[r] + rs;
    }

#pragma unroll
    for (int dt = 0; dt < 4; ++dt)
#pragma unroll
      for (int r = 0; r < 4; ++r) oacc[dt][r] *= alpha[r];

    // ---- O += P @ V  (P: A-layout from LDS, V: B-layout from transposed Vt)
    bf16x8 pf0 = *(const bf16x8*)&Ps[w][l16 * 64 + quad * 8];
    bf16x8 pf1 = *(const bf16x8*)&Ps[w][l16 * 64 + 32 + quad * 8];
#pragma unroll
    for (int dt = 0; dt < 4; ++dt) {
      bf16x8 vf0 = *(const bf16x8*)&Vt[(dt * 16 + l16) * LDV + quad * 8];
      bf16x8 vf1 = *(const bf16x8*)&Vt[(dt * 16 + l16) * LDV + 32 + quad * 8];
      oacc[dt] = MFMA16(pf0, vf0, oacc[dt]);
      oacc[dt] = MFMA16(pf1, vf1, oacc[dt]);
    }
  }

  // ---- normalize + store O[b, l, h*64+d]
#pragma unroll
  for (int dt = 0; dt < 4; ++dt) {
#pragma unroll
    for (int r = 0; r < 4; ++r) {
      const float val = oacc[dt][r] / lrun[r];
      const int l = qt * 64 + w * 16 + quad * 4 + r;
      O[(size_t)(b * 4096 + l) * DIM + h * 64 + dt * 16 + l16] = (bf16)val;
    }
  }
}

// ---------------------------------------------------------------------------
extern "C" void kernel_launch(void* const* d_in, const int* in_sizes, int n_in,
                              void* d_out, int out_size, void* d_ws, size_t ws_size,
                              hipStream_t stream) {
  const float* x_broad = (const float*)d_in[0];
  const float* x_low = (const float*)d_in[1];
  const float* Wq = (const float*)d_in[2];
  const float* bq = (const float*)d_in[3];
  const float* Wk = (const float*)d_in[4];
  const float* bk = (const float*)d_in[5];
  const float* Wv = (const float*)d_in[6];
  const float* bv = (const float*)d_in[7];
  const float* Wo = (const float*)d_in[8];
  const float* bo = (const float*)d_in[9];

  constexpr int B = 4, L = 4096, LL = 1024;

  // workspace layout (bf16): Q[B,NH,L,64] | K[B,NH,LL,64] | V[B,NH,LL,64] | O[B,L,DIM]
  char* ws = (char*)d_ws;
  const size_t qBytes = (size_t)B * NH * L * HD * sizeof(bf16);   // 33.5 MB
  const size_t kvBytes = (size_t)B * NH * LL * HD * sizeof(bf16); //  8.4 MB each
  bf16* Qw = (bf16*)ws;
  bf16* Kw = (bf16*)(ws + qBytes);
  bf16* Vw = (bf16*)(ws + qBytes + kvBytes);
  bf16* Ow = (bf16*)(ws + qBytes + 2 * kvBytes);

  const dim3 blk(256);
  hipLaunchKernelGGL((gemm_nt<true, false>), dim3(B * L / 128, DIM / 128), blk, 0,
                     stream, x_broad, Wq, bq, Qw, L);
  hipLaunchKernelGGL((gemm_nt<true, false>), dim3(B * LL / 128, DIM / 128), blk, 0,
                     stream, x_low, Wk, bk, Kw, LL);
  hipLaunchKernelGGL((gemm_nt<true, false>), dim3(B * LL / 128, DIM / 128), blk, 0,
                     stream, x_low, Wv, bv, Vw, LL);
  hipLaunchKernelGGL(attn_fused, dim3(L / 64, NH, B), blk, 0, stream, Qw, Kw, Vw, Ow);
  hipLaunchKernelGGL((gemm_nt<false, true>), dim3(B * L / 128, DIM / 128), blk, 0,
                     stream, Ow, Wo, bo, d_out, 1);
}